// Round 1
// baseline (189.623 us; speedup 1.0000x reference)
//
#include <hip/hip_runtime.h>

// LSTM: IN=2, HID=4, OUT=2, B=8192, T=1024.
// 4 lanes per batch element: lane j owns hidden unit j (computes gates
// i_j, f_j, g_j, o_j; c_j update is lane-local). h all-gather via DPP
// quad_perm (VALU-speed cross-lane within the aligned quad).
// Gate weights pre-scaled by -log2(e) (g gate by -2log2(e)) so
// sigmoid(x) = rcp(1 + exp2(xhat)), tanh(x) = 2*rcp(1+exp2(xhat)) - 1.

#define T_LEN 1024

template <int C>
__device__ __forceinline__ float qperm(float v) {
  return __builtin_bit_cast(
      float, __builtin_amdgcn_mov_dpp(__builtin_bit_cast(int, v), C, 0xf, 0xf, true));
}

__global__ __launch_bounds__(64) void lstm_fused(
    const float* __restrict__ x, const float* __restrict__ w_ih,
    const float* __restrict__ w_hh, const float* __restrict__ b_ih,
    const float* __restrict__ b_hh, const float* __restrict__ w_lin,
    const float* __restrict__ b_lin, float* __restrict__ out) {
  const int gid = blockIdx.x * 64 + threadIdx.x;
  const int b = gid >> 2;   // batch element
  const int j = gid & 3;    // hidden unit owned by this lane

  const float L2E = 1.4426950408889634f;
  const float KTC = -2.0f * L2E;

  // Per-lane weight registers; h-columns permuted by j^m so that the
  // DPP-gathered registers r_m = h_{j^m} line up with the weights.
  float wih[4][2], whh[4][4], bias[4];
#pragma unroll
  for (int g = 0; g < 4; ++g) {
    const float sc = (g == 2) ? (-2.0f * L2E) : (-L2E);
    const int row = g * 4 + j;  // PyTorch gate order [i,f,g,o] x HID
    wih[g][0] = w_ih[row * 2 + 0] * sc;
    wih[g][1] = w_ih[row * 2 + 1] * sc;
#pragma unroll
    for (int m = 0; m < 4; ++m) whh[g][m] = w_hh[row * 4 + (j ^ m)] * sc;
    bias[g] = (b_ih[row] + b_hh[row]) * sc;
  }
  float wl[4];
  const int o = j & 1;  // lanes 0,2 compute out0; lanes 1,3 compute out1
#pragma unroll
  for (int m = 0; m < 4; ++m) wl[m] = w_lin[o * 4 + (j ^ m)];
  const float bl = b_lin[o];

  float cc = 0.0f;                                  // cell state c_j
  float r0 = 0.0f, r1 = 0.0f, r2 = 0.0f, r3 = 0.0f; // h_{j^0..3}

  const float4* xp4 = (const float4*)(x + (size_t)b * (T_LEN * 2));
  float* optr = out + (size_t)b * (T_LEN * 2) + j;
  const bool st = (j < 2);

  // 8-step window = 64 B of x = one cache line; double-buffered prefetch.
  float4 c0 = xp4[0], c1 = xp4[1], c2 = xp4[2], c3 = xp4[3];

  for (int w = 0; w < T_LEN / 8; ++w) {
    float4 n0, n1, n2, n3;
    if (w + 1 < T_LEN / 8) {
      const float4* p = xp4 + (size_t)(w + 1) * 4;
      n0 = p[0]; n1 = p[1]; n2 = p[2]; n3 = p[3];
    } else {
      n0 = c0; n1 = c1; n2 = c2; n3 = c3;
    }

#define STEP(X0, X1)                                                         \
  do {                                                                       \
    float a0 = fmaf((X0), wih[0][0], bias[0]); a0 = fmaf((X1), wih[0][1], a0); \
    float a1 = fmaf((X0), wih[1][0], bias[1]); a1 = fmaf((X1), wih[1][1], a1); \
    float a2 = fmaf((X0), wih[2][0], bias[2]); a2 = fmaf((X1), wih[2][1], a2); \
    float a3 = fmaf((X0), wih[3][0], bias[3]); a3 = fmaf((X1), wih[3][1], a3); \
    a0 = fmaf(r0, whh[0][0], a0); a0 = fmaf(r1, whh[0][1], a0);              \
    a0 = fmaf(r2, whh[0][2], a0); a0 = fmaf(r3, whh[0][3], a0);              \
    a1 = fmaf(r0, whh[1][0], a1); a1 = fmaf(r1, whh[1][1], a1);              \
    a1 = fmaf(r2, whh[1][2], a1); a1 = fmaf(r3, whh[1][3], a1);              \
    a2 = fmaf(r0, whh[2][0], a2); a2 = fmaf(r1, whh[2][1], a2);              \
    a2 = fmaf(r2, whh[2][2], a2); a2 = fmaf(r3, whh[2][3], a2);              \
    a3 = fmaf(r0, whh[3][0], a3); a3 = fmaf(r1, whh[3][1], a3);              \
    a3 = fmaf(r2, whh[3][2], a3); a3 = fmaf(r3, whh[3][3], a3);              \
    float e0 = __builtin_amdgcn_exp2f(a0);                                   \
    float e1 = __builtin_amdgcn_exp2f(a1);                                   \
    float e2 = __builtin_amdgcn_exp2f(a2);                                   \
    float e3 = __builtin_amdgcn_exp2f(a3);                                   \
    float si = __builtin_amdgcn_rcpf(1.0f + e0);                             \
    float sf = __builtin_amdgcn_rcpf(1.0f + e1);                             \
    float tg = fmaf(2.0f, __builtin_amdgcn_rcpf(1.0f + e2), -1.0f);          \
    float so = __builtin_amdgcn_rcpf(1.0f + e3);                             \
    cc = fmaf(sf, cc, si * tg);                                              \
    float et = __builtin_amdgcn_exp2f(cc * KTC);                             \
    float tc = fmaf(2.0f, __builtin_amdgcn_rcpf(1.0f + et), -1.0f);          \
    float h = so * tc;                                                       \
    r0 = h;                                                                  \
    r1 = qperm<0xB1>(h); /* lane ^ 1 */                                      \
    r2 = qperm<0x4E>(h); /* lane ^ 2 */                                      \
    r3 = qperm<0x1B>(h); /* lane ^ 3 */                                      \
    float ov = fmaf(r0, wl[0], bl);                                          \
    ov = fmaf(r1, wl[1], ov);                                                \
    ov = fmaf(r2, wl[2], ov);                                                \
    ov = fmaf(r3, wl[3], ov);                                                \
    if (st) *optr = ov;                                                      \
    optr += 2;                                                               \
  } while (0)

    STEP(c0.x, c0.y); STEP(c0.z, c0.w);
    STEP(c1.x, c1.y); STEP(c1.z, c1.w);
    STEP(c2.x, c2.y); STEP(c2.z, c2.w);
    STEP(c3.x, c3.y); STEP(c3.z, c3.w);
#undef STEP

    c0 = n0; c1 = n1; c2 = n2; c3 = n3;
  }
}

extern "C" void kernel_launch(void* const* d_in, const int* in_sizes, int n_in,
                              void* d_out, int out_size, void* d_ws, size_t ws_size,
                              hipStream_t stream) {
  const float* x     = (const float*)d_in[0];
  const float* w_ih  = (const float*)d_in[1];
  const float* w_hh  = (const float*)d_in[2];
  const float* b_ih  = (const float*)d_in[3];
  const float* b_hh  = (const float*)d_in[4];
  const float* w_lin = (const float*)d_in[5];
  const float* b_lin = (const float*)d_in[6];
  float* out = (float*)d_out;

  // 8192 batches * 4 lanes = 32768 threads; 1 wave per block -> 512 blocks
  // spread over 256 CUs (2 waves/CU).
  lstm_fused<<<512, 64, 0, stream>>>(x, w_ih, w_hh, b_ih, b_hh, w_lin, b_lin, out);
}

// Round 2
// 156.075 us; speedup vs baseline: 1.2149x; 1.2149x over previous
//
#include <hip/hip_runtime.h>

// LSTM: IN=2, HID=4, OUT=2, B=8192, T=1024.
// 4 lanes per batch element; lane j owns hidden unit j. Latency-bound on the
// serial recurrence -> everything is organized to minimize the per-step
// dependency chain:
//   h -> [3-level FMA tree] -> exp2 -> add -> rcp -> fma(tgK) -> mul ->
//   fma(d) -> exp2 -> add -> rcp -> fma(h) -> DPP -> next step
// Cell state carried pre-scaled: d = KTC*c, KTC = -2*log2(e), so tanh(c)
// needs no extra multiplies. Gate weights pre-scaled by -log2(e)
// (g gate by -2log2(e)): sigmoid(z) = rcp(1 + exp2(-z*log2e)).
// x loads: per-lane float4 (coalesced 64B/quad), 2-window prefetch,
// quad-broadcast DPP distribution (off-chain).
// Outputs: buffered 8 steps in regs, one coalesced float4 store per lane
// per window (no per-step stores on the chain).

#define T_LEN 1024
#define NW (T_LEN / 8)

template <int C>
__device__ __forceinline__ float qp(float v) {
  return __builtin_bit_cast(
      float, __builtin_amdgcn_mov_dpp(__builtin_bit_cast(int, v), C, 0xf, 0xf, true));
}

__global__ __launch_bounds__(64) void lstm_fused(
    const float* __restrict__ x, const float* __restrict__ w_ih,
    const float* __restrict__ w_hh, const float* __restrict__ b_ih,
    const float* __restrict__ b_hh, const float* __restrict__ w_lin,
    const float* __restrict__ b_lin, float* __restrict__ out) {
  const int gid = blockIdx.x * 64 + threadIdx.x;
  const int b = gid >> 2;
  const int j = gid & 3;

  const float L2E = 1.4426950408889634f;
  const float KTC = -2.0f * L2E;            // d = KTC * c
  const float TWOKTC = 2.0f * KTC;
  const float NEGKTC = -KTC;

  float wih[4][2], whh[4][4], bias[4];
#pragma unroll
  for (int g = 0; g < 4; ++g) {
    const float sc = (g == 2) ? (-2.0f * L2E) : (-L2E);
    const int row = g * 4 + j;  // PyTorch gate order [i,f,g,o] x HID
    wih[g][0] = w_ih[row * 2 + 0] * sc;
    wih[g][1] = w_ih[row * 2 + 1] * sc;
#pragma unroll
    for (int m = 0; m < 4; ++m) whh[g][m] = w_hh[row * 4 + (j ^ m)] * sc;
    bias[g] = (b_ih[row] + b_hh[row]) * sc;
  }
  float wl[4];
  const int o = j & 1;
#pragma unroll
  for (int m = 0; m < 4; ++m) wl[m] = w_lin[o * 4 + (j ^ m)];
  const float bl = b_lin[o];

  float d = 0.0f;                                   // scaled cell state
  float r0 = 0.0f, r1 = 0.0f, r2 = 0.0f, r3 = 0.0f; // h_{j^0..3}

  // Per-lane float4: floats [w*16 + 4j .. +3] = steps 2j, 2j+1 of window w.
  const float4* xq = (const float4*)(x + (size_t)b * (T_LEN * 2));
  float4* outq = (float4*)(out + (size_t)b * (T_LEN * 2));

  float4 xa = xq[0 * 4 + j];
  float4 xb_ = xq[1 * 4 + j];

  for (int w = 0; w < NW; ++w) {
    const int wn = (w + 2 < NW) ? (w + 2) : w;  // clamped redundant tail load
    float4 xc = xq[wn * 4 + j];

    float ov[8], po[8];

#define GATE(g)                                                    \
  float ax_##g = fmaf(X1, wih[g][1], fmaf(X0, wih[g][0], bias[g])); \
  float t1_##g = fmaf(r1, whh[g][1], ax_##g);                      \
  float t2_##g = r2 * whh[g][2];                                   \
  float t3_##g = fmaf(r0, whh[g][0], t1_##g);                      \
  float t4_##g = fmaf(r3, whh[g][3], t2_##g);                      \
  float a_##g = t3_##g + t4_##g;

#define STEP(s)                                                            \
  do {                                                                     \
    const float X0 = qp<(((s) >> 1) * 0x55)>(((s)&1) ? xa.z : xa.x);       \
    const float X1 = qp<(((s) >> 1) * 0x55)>(((s)&1) ? xa.w : xa.y);       \
    GATE(0) GATE(1) GATE(2) GATE(3)                                        \
    float ei = __builtin_amdgcn_exp2f(a_0);                                \
    float ef = __builtin_amdgcn_exp2f(a_1);                                \
    float eg = __builtin_amdgcn_exp2f(a_2);                                \
    float eo = __builtin_amdgcn_exp2f(a_3);                                \
    float si = __builtin_amdgcn_rcpf(1.0f + ei);                           \
    float sf = __builtin_amdgcn_rcpf(1.0f + ef);                           \
    float rg = __builtin_amdgcn_rcpf(1.0f + eg);                           \
    float so = __builtin_amdgcn_rcpf(1.0f + eo);                           \
    float tgK = fmaf(rg, TWOKTC, NEGKTC); /* = KTC*tanh(g) */              \
    float it = si * tgK;                                                   \
    d = fmaf(sf, d, it);                                                   \
    float ec = __builtin_amdgcn_exp2f(d);                                  \
    float rc = __builtin_amdgcn_rcpf(1.0f + ec);                           \
    float h = fmaf(so + so, rc, -so); /* = so * tanh(c) */                 \
    r0 = h;                                                                \
    r1 = qp<0xB1>(h);                                                      \
    r2 = qp<0x4E>(h);                                                      \
    r3 = qp<0x1B>(h);                                                      \
    float o_ = fmaf(r3, wl[3], fmaf(r2, wl[2], fmaf(r1, wl[1],             \
                    fmaf(r0, wl[0], bl))));                                \
    ov[s] = o_;                                                            \
    po[s] = qp<0xB1>(o_);                                                  \
  } while (0)

    STEP(0); STEP(1); STEP(2); STEP(3);
    STEP(4); STEP(5); STEP(6); STEP(7);
#undef STEP
#undef GATE

    // Coalesced output: lane k stores steps 2k,2k+1 as one float4.
    // Even lanes hold o0 in ov / o1 in po; odd lanes the reverse.
    if (j == 0) { float4 v = {ov[0], po[0], ov[1], po[1]}; outq[w * 4 + 0] = v; }
    if (j == 1) { float4 v = {po[2], ov[2], po[3], ov[3]}; outq[w * 4 + 1] = v; }
    if (j == 2) { float4 v = {ov[4], po[4], ov[5], po[5]}; outq[w * 4 + 2] = v; }
    if (j == 3) { float4 v = {po[6], ov[6], po[7], ov[7]}; outq[w * 4 + 3] = v; }

    xa = xb_;
    xb_ = xc;
  }
}

extern "C" void kernel_launch(void* const* d_in, const int* in_sizes, int n_in,
                              void* d_out, int out_size, void* d_ws, size_t ws_size,
                              hipStream_t stream) {
  const float* x     = (const float*)d_in[0];
  const float* w_ih  = (const float*)d_in[1];
  const float* w_hh  = (const float*)d_in[2];
  const float* b_ih  = (const float*)d_in[3];
  const float* b_hh  = (const float*)d_in[4];
  const float* w_lin = (const float*)d_in[5];
  const float* b_lin = (const float*)d_in[6];
  float* out = (float*)d_out;

  lstm_fused<<<512, 64, 0, stream>>>(x, w_ih, w_hh, b_ih, b_hh, w_lin, b_lin, out);
}

// Round 3
// 155.353 us; speedup vs baseline: 1.2206x; 1.0047x over previous
//
#include <hip/hip_runtime.h>

// LSTM: IN=2, HID=4, OUT=2, B=8192, T=1024.
// 4 lanes per batch element; lane j owns hidden unit j. Latency-bound on the
// serial recurrence; per-step dependency chain:
//   h -> [3-level FMA tree] -> exp2 -> add -> rcp -> fma(tgK) -> mul ->
//   fma(d) -> exp2 -> add -> rcp -> fma(h) -> DPP -> next step
// Cell state carried pre-scaled: d = KTC*c, KTC = -2*log2(e). Gate weights
// pre-scaled by -log2(e) (g gate by -2log2(e)).
// __launch_bounds__(64, 1): min 1 wave/EU so the register allocator keeps
// ALL weights + prefetch + output buffers in VGPRs (prev build got squeezed
// to 36 VGPRs targeting 8 waves/EU and re-loaded weights in-loop -> ~250
// stall cycles/step on vmcnt).

#define T_LEN 1024
#define NW (T_LEN / 8)

template <int C>
__device__ __forceinline__ float qp(float v) {
  return __builtin_bit_cast(
      float, __builtin_amdgcn_mov_dpp(__builtin_bit_cast(int, v), C, 0xf, 0xf, true));
}

__global__ __launch_bounds__(64, 1) void lstm_fused(
    const float* __restrict__ x, const float* __restrict__ w_ih,
    const float* __restrict__ w_hh, const float* __restrict__ b_ih,
    const float* __restrict__ b_hh, const float* __restrict__ w_lin,
    const float* __restrict__ b_lin, float* __restrict__ out) {
  const int gid = blockIdx.x * 64 + threadIdx.x;
  const int b = gid >> 2;
  const int j = gid & 3;

  const float L2E = 1.4426950408889634f;
  const float KTC = -2.0f * L2E;            // d = KTC * c
  const float TWOKTC = 2.0f * KTC;
  const float NEGKTC = -KTC;

  float wih[4][2], whh[4][4], bias[4];
#pragma unroll
  for (int g = 0; g < 4; ++g) {
    const float sc = (g == 2) ? (-2.0f * L2E) : (-L2E);
    const int row = g * 4 + j;  // PyTorch gate order [i,f,g,o] x HID
    wih[g][0] = w_ih[row * 2 + 0] * sc;
    wih[g][1] = w_ih[row * 2 + 1] * sc;
#pragma unroll
    for (int m = 0; m < 4; ++m) whh[g][m] = w_hh[row * 4 + (j ^ m)] * sc;
    bias[g] = (b_ih[row] + b_hh[row]) * sc;
  }
  float wl[4];
  const int o = j & 1;
#pragma unroll
  for (int m = 0; m < 4; ++m) wl[m] = w_lin[o * 4 + (j ^ m)];
  const float bl = b_lin[o];

  float d = 0.0f;                                   // scaled cell state
  float r0 = 0.0f, r1 = 0.0f, r2 = 0.0f, r3 = 0.0f; // h_{j^0..3}

  // Per-lane float4: floats [w*16 + 4j .. +3] = steps 2j, 2j+1 of window w.
  const float4* xq = (const float4*)(x + (size_t)b * (T_LEN * 2));
  float4* outq = (float4*)(out + (size_t)b * (T_LEN * 2));

  float4 xa = xq[0 * 4 + j];
  float4 xb_ = xq[1 * 4 + j];

  for (int w = 0; w < NW; ++w) {
    const int wn = (w + 2 < NW) ? (w + 2) : w;  // clamped redundant tail load
    float4 xc = xq[wn * 4 + j];

    float ov[8], po[8];

#define GATE(g)                                                    \
  float ax_##g = fmaf(X1, wih[g][1], fmaf(X0, wih[g][0], bias[g])); \
  float t1_##g = fmaf(r1, whh[g][1], ax_##g);                      \
  float t2_##g = r2 * whh[g][2];                                   \
  float t3_##g = fmaf(r0, whh[g][0], t1_##g);                      \
  float t4_##g = fmaf(r3, whh[g][3], t2_##g);                      \
  float a_##g = t3_##g + t4_##g;

#define STEP(s)                                                            \
  do {                                                                     \
    const float X0 = qp<(((s) >> 1) * 0x55)>(((s)&1) ? xa.z : xa.x);       \
    const float X1 = qp<(((s) >> 1) * 0x55)>(((s)&1) ? xa.w : xa.y);       \
    GATE(0) GATE(1) GATE(2) GATE(3)                                        \
    float ei = __builtin_amdgcn_exp2f(a_0);                                \
    float ef = __builtin_amdgcn_exp2f(a_1);                                \
    float eg = __builtin_amdgcn_exp2f(a_2);                                \
    float eo = __builtin_amdgcn_exp2f(a_3);                                \
    float si = __builtin_amdgcn_rcpf(1.0f + ei);                           \
    float sf = __builtin_amdgcn_rcpf(1.0f + ef);                           \
    float rg = __builtin_amdgcn_rcpf(1.0f + eg);                           \
    float so = __builtin_amdgcn_rcpf(1.0f + eo);                           \
    float tgK = fmaf(rg, TWOKTC, NEGKTC); /* = KTC*tanh(g) */              \
    float it = si * tgK;                                                   \
    d = fmaf(sf, d, it);                                                   \
    float ec = __builtin_amdgcn_exp2f(d);                                  \
    float rc = __builtin_amdgcn_rcpf(1.0f + ec);                           \
    float h = fmaf(so + so, rc, -so); /* = so * tanh(c) */                 \
    r0 = h;                                                                \
    r1 = qp<0xB1>(h);                                                      \
    r2 = qp<0x4E>(h);                                                      \
    r3 = qp<0x1B>(h);                                                      \
    float o_ = fmaf(r3, wl[3], fmaf(r2, wl[2], fmaf(r1, wl[1],             \
                    fmaf(r0, wl[0], bl))));                                \
    ov[s] = o_;                                                            \
    po[s] = qp<0xB1>(o_);                                                  \
  } while (0)

    STEP(0); STEP(1); STEP(2); STEP(3);
    STEP(4); STEP(5); STEP(6); STEP(7);
#undef STEP
#undef GATE

    // Coalesced output: lane k stores steps 2k,2k+1 as one float4.
    // Even lanes hold o0 in ov / o1 in po; odd lanes the reverse.
    if (j == 0) { float4 v = {ov[0], po[0], ov[1], po[1]}; outq[w * 4 + 0] = v; }
    if (j == 1) { float4 v = {po[2], ov[2], po[3], ov[3]}; outq[w * 4 + 1] = v; }
    if (j == 2) { float4 v = {ov[4], po[4], ov[5], po[5]}; outq[w * 4 + 2] = v; }
    if (j == 3) { float4 v = {po[6], ov[6], po[7], ov[7]}; outq[w * 4 + 3] = v; }

    xa = xb_;
    xb_ = xc;
  }
}

extern "C" void kernel_launch(void* const* d_in, const int* in_sizes, int n_in,
                              void* d_out, int out_size, void* d_ws, size_t ws_size,
                              hipStream_t stream) {
  const float* x     = (const float*)d_in[0];
  const float* w_ih  = (const float*)d_in[1];
  const float* w_hh  = (const float*)d_in[2];
  const float* b_ih  = (const float*)d_in[3];
  const float* b_hh  = (const float*)d_in[4];
  const float* w_lin = (const float*)d_in[5];
  const float* b_lin = (const float*)d_in[6];
  float* out = (float*)d_out;

  lstm_fused<<<512, 64, 0, stream>>>(x, w_ih, w_hh, b_ih, b_hh, w_lin, b_lin, out);
}

// Round 4
// 140.001 us; speedup vs baseline: 1.3544x; 1.1097x over previous
//
#include <hip/hip_runtime.h>

// LSTM: IN=2, HID=4, OUT=2, B=8192, T=1024.
// 16 lanes per batch element: lane = gate*4 + unit (gate-major).
// Each lane computes ONE gate pre-activation + ONE nonlinearity per step
// (2 transcendentals/step vs 10 in the 4-lane version), then:
//   - named gate values {si, sf, KTC*tanh(g), so} broadcast to all lanes of
//     the 16-lane group via ds_swizzle BitMode (and=0x13 keeps unit bits +
//     the 16-group bit within 32; or=4*gate selects the gate quad),
//   - all lanes redundantly update d = KTC*c and h_j (j = lane&3),
//   - h all-gather for the next step's tree via quad_perm ^1/^2/^3 with the
//     proven j^m weight permutation (each quad holds h_0..h_3).
// 8192*16 = 131072 threads = 2048 waves = 2 waves/SIMD on all 1024 SIMDs:
// the second wave fills the first's dependency-chain stalls.
// Cell state carried pre-scaled: d = KTC*c, KTC = -2*log2(e). Gate weights
// pre-scaled by -log2(e) (g gate by -2*log2(e)).

#define T_LEN 1024
#define NW (T_LEN / 8)

template <int C>
__device__ __forceinline__ float qp(float v) {
  return __builtin_bit_cast(float,
      __builtin_amdgcn_mov_dpp(__builtin_bit_cast(int, v), C, 0xf, 0xf, true));
}

template <int OFS>
__device__ __forceinline__ float swz(float v) {
  return __builtin_bit_cast(float,
      __builtin_amdgcn_ds_swizzle(__builtin_bit_cast(int, v), OFS));
}

// ds_swizzle BitMode offsets: src = ((lane & AND) | OR), AND=0x13 keeps
// unit bits {0,1} + bit4 (which 16-group inside the 32-half).
#define SW_I 0x0013
#define SW_F 0x0093
#define SW_G 0x0113
#define SW_O 0x0193

__global__ __launch_bounds__(256, 2) void lstm_fused(
    const float* __restrict__ x, const float* __restrict__ w_ih,
    const float* __restrict__ w_hh, const float* __restrict__ b_ih,
    const float* __restrict__ b_hh, const float* __restrict__ w_lin,
    const float* __restrict__ b_lin, float* __restrict__ out) {
  const int tid = blockIdx.x * 256 + threadIdx.x;
  const int b = tid >> 4;    // batch element (one per 16-lane group)
  const int l = tid & 15;    // lane within group
  const int j = l & 3;       // hidden unit
  const int gi = l >> 2;     // gate index: 0=i 1=f 2=g 3=o

  const float L2E = 1.4426950408889634f;
  const float KTC = -2.0f * L2E;  // d = KTC * c

  // Per-lane weights for gate gi, unit j (PyTorch row = gi*4 + j).
  const int row = gi * 4 + j;
  const float sc = (gi == 2) ? (-2.0f * L2E) : (-L2E);
  const float wih0 = w_ih[row * 2 + 0] * sc;
  const float wih1 = w_ih[row * 2 + 1] * sc;
  const float bias = (b_ih[row] + b_hh[row]) * sc;
  float whh[4];
#pragma unroll
  for (int m = 0; m < 4; ++m) whh[m] = w_hh[row * 4 + (j ^ m)] * sc;
  // Post-rcp uniform fma: sigmoid lanes -> val = rcp; g lane -> KTC*tanh(g).
  const float PA = (gi == 2) ? (2.0f * KTC) : 1.0f;
  const float PB = (gi == 2) ? (-KTC) : 0.0f;
  // Output projection (redundant on all lanes, parity picks the column).
  const int o = l & 1;
  float wl[4];
#pragma unroll
  for (int m = 0; m < 4; ++m) wl[m] = w_lin[o * 4 + (j ^ m)];
  const float blv = b_lin[o];
  const int sl = l >> 1;  // the step this lane stores (keep-lane select)

  float d = 0.0f;                                   // scaled cell state
  float r0 = 0.0f, r1 = 0.0f, r2 = 0.0f, r3 = 0.0f; // h_{j^0..3}

  // x: all 16 lanes of a group load the same float4s (HW broadcast).
  const float4* xq = (const float4*)(x + (size_t)b * (T_LEN * 2));
  float* op = out + (size_t)b * (T_LEN * 2) + l;  // group-window base + lane

  float4 xa0 = xq[0], xa1 = xq[1], xa2 = xq[2], xa3 = xq[3];
  float4 xb0 = xq[4], xb1 = xq[5], xb2 = xq[6], xb3 = xq[7];

  for (int w = 0; w < NW; ++w) {
    const int wn = (w + 2 < NW) ? (w + 2) : w;  // clamped tail prefetch
    const float4* pn = xq + (size_t)wn * 4;
    float4 xc0 = pn[0], xc1 = pn[1], xc2 = pn[2], xc3 = pn[3];

    float keep = 0.0f;

#define STEP(s, X0, X1)                                                    \
  do {                                                                     \
    float ax = fmaf((X1), wih1, fmaf((X0), wih0, bias));                   \
    float t1 = fmaf(r1, whh[1], ax);                                       \
    float t2 = fmaf(r3, whh[3], r2 * whh[2]);                              \
    float t0 = fmaf(r0, whh[0], t1);                                       \
    float a = t0 + t2;                                                     \
    float e = __builtin_amdgcn_exp2f(a);                                   \
    float rr = __builtin_amdgcn_rcpf(1.0f + e);                            \
    float val = fmaf(rr, PA, PB);                                          \
    float si = swz<SW_I>(val);                                             \
    float sf = swz<SW_F>(val);                                             \
    float tg = swz<SW_G>(val); /* = KTC*tanh(g) */                         \
    float so = swz<SW_O>(val);                                             \
    d = fmaf(sf, d, si * tg);                                              \
    float ec = __builtin_amdgcn_exp2f(d);                                  \
    float rc = __builtin_amdgcn_rcpf(1.0f + ec);                           \
    float h = fmaf(so + so, rc, -so); /* = so*tanh(c) */                   \
    r0 = h;                                                                \
    r1 = qp<0xB1>(h);                                                      \
    r2 = qp<0x4E>(h);                                                      \
    r3 = qp<0x1B>(h);                                                      \
    float ov = fmaf(r3, wl[3], fmaf(r2, wl[2],                             \
                    fmaf(r1, wl[1], fmaf(r0, wl[0], blv))));               \
    if (sl == (s)) keep = ov;                                              \
  } while (0)

    STEP(0, xa0.x, xa0.y); STEP(1, xa0.z, xa0.w);
    STEP(2, xa1.x, xa1.y); STEP(3, xa1.z, xa1.w);
    STEP(4, xa2.x, xa2.y); STEP(5, xa2.z, xa2.w);
    STEP(6, xa3.x, xa3.y); STEP(7, xa3.z, xa3.w);
#undef STEP

    // Lane l stores out[b, w*8 + l/2, l&1] = flat b*2048 + w*16 + l.
    op[w * 16] = keep;

    xa0 = xb0; xa1 = xb1; xa2 = xb2; xa3 = xb3;
    xb0 = xc0; xb1 = xc1; xb2 = xc2; xb3 = xc3;
  }
}

extern "C" void kernel_launch(void* const* d_in, const int* in_sizes, int n_in,
                              void* d_out, int out_size, void* d_ws, size_t ws_size,
                              hipStream_t stream) {
  const float* x     = (const float*)d_in[0];
  const float* w_ih  = (const float*)d_in[1];
  const float* w_hh  = (const float*)d_in[2];
  const float* b_ih  = (const float*)d_in[3];
  const float* b_hh  = (const float*)d_in[4];
  const float* w_lin = (const float*)d_in[5];
  const float* b_lin = (const float*)d_in[6];
  float* out = (float*)d_out;

  // 8192 groups * 16 lanes = 131072 threads = 2048 waves (2 per SIMD).
  lstm_fused<<<512, 256, 0, stream>>>(x, w_ih, w_hh, b_ih, b_hh, w_lin, b_lin, out);
}